// Round 1
// baseline (345.616 us; speedup 1.0000x reference)
//
#include <hip/hip_runtime.h>
#include <stdint.h>

typedef _Float16 f16;
typedef __attribute__((ext_vector_type(8))) _Float16 f16x8;
typedef __attribute__((ext_vector_type(4))) _Float16 f16x4;
typedef __attribute__((ext_vector_type(4))) float f32x4;

#define BM 128
#define BN 128
#define BK 32

typedef __attribute__((address_space(3))) uint32_t lds_u32;
typedef const __attribute__((address_space(1))) uint32_t glb_u32;

__device__ __forceinline__ void gload_lds16(const void* g, void* l) {
    // async global->LDS, 16B per lane; LDS dest = wave-uniform base + lane*16
    __builtin_amdgcn_global_load_lds((glb_u32*)g, (lds_u32*)l, 16, 0, 0);
}

// C[M,N] = A[M,K] * B[N,K]^T  (both f16 row-major), fp32 accumulate.
// OUT_MODE: 0 = fp32 out, 1 = f16 out, 2 = f16 transposed out (C^T, [N,M])
// CAUSAL: 0 = none, 1 = skip blocks with n0 > m0 (scores QK^T), 2 = K-loop limit m0+BM (PV)
template<int OUT_MODE, int CAUSAL>
__global__ __launch_bounds__(256, 2)
void gemm_bt(const f16* __restrict__ A, const f16* __restrict__ B,
             const float* __restrict__ bias, void* __restrict__ Cv,
             int M, int N, int K,
             long long sAb, long long sBb, long long sCb, float scale)
{
    const int m0 = blockIdx.y * BM;
    const int n0 = blockIdx.x * BN;
    if (CAUSAL == 1 && n0 > m0) return;   // fully-masked score block
    const int Kend = (CAUSAL == 2) ? (m0 + BM) : K;  // P[q][k]==0 for k>q

    const int tid  = threadIdx.x;
    const int wave = tid >> 6;
    const int lane = tid & 63;
    const long long bz = blockIdx.z;
    A += bz * sAb;
    B += bz * sBb;

    __shared__ f16 As[BM * BK];  // A tile, rows = m
    __shared__ f16 Bs[BM * BK];  // B^T tile, rows = n (both [128][32], 64B rows)

    const int wm = (wave >> 1) * 64;
    const int wn = (wave & 1) * 64;

    f32x4 acc[4][4] = {};

    const int srow = lane >> 2;         // staging: row within 16-row group
    const int scol = (lane & 3) * 8;    // staging: 8-elem (16B) chunk in row
    const int fr   = lane & 15;         // frag: m (A) / n (B) within 16-tile
    const int fk   = (lane >> 4) * 8;   // frag: k offset (quad*8)

    for (int k0 = 0; k0 < Kend; k0 += BK) {
        #pragma unroll
        for (int i = 0; i < 2; ++i) {
            const int r = wave * 32 + i * 16;  // wave-uniform 16-row group
            gload_lds16(A + (long long)(m0 + r + srow) * K + (k0 + scol), &As[r * BK]);
            gload_lds16(B + (long long)(n0 + r + srow) * K + (k0 + scol), &Bs[r * BK]);
        }
        __syncthreads();

        f16x8 af[4], bf[4];
        #pragma unroll
        for (int i = 0; i < 4; ++i)
            af[i] = *(const f16x8*)&As[(wm + i * 16 + fr) * BK + fk];
        #pragma unroll
        for (int j = 0; j < 4; ++j)
            bf[j] = *(const f16x8*)&Bs[(wn + j * 16 + fr) * BK + fk];

        #pragma unroll
        for (int i = 0; i < 4; ++i)
            #pragma unroll
            for (int j = 0; j < 4; ++j)
                acc[i][j] = __builtin_amdgcn_mfma_f32_16x16x32_f16(af[i], bf[j], acc[i][j], 0, 0, 0);
        __syncthreads();
    }

    // Epilogue. C/D layout: col = lane&15, row = (lane>>4)*4 + reg  [measured m89/m91]
    const int cn = lane & 15;
    const int cm = (lane >> 4) * 4;
    #pragma unroll
    for (int j = 0; j < 4; ++j) {
        const int gn = n0 + wn + j * 16 + cn;
        const float bv = bias ? bias[gn] : 0.f;
        #pragma unroll
        for (int i = 0; i < 4; ++i) {
            const int gm = m0 + wm + i * 16 + cm;
            if (OUT_MODE == 0) {
                float* C = (float*)Cv + bz * sCb;
                #pragma unroll
                for (int r = 0; r < 4; ++r)
                    C[(long long)(gm + r) * N + gn] = acc[i][j][r] * scale + bv;
            } else if (OUT_MODE == 1) {
                f16* C = (f16*)Cv + bz * sCb;
                #pragma unroll
                for (int r = 0; r < 4; ++r)
                    C[(long long)(gm + r) * N + gn] = (f16)(acc[i][j][r] * scale + bv);
            } else {  // transposed store: C^T[n][m], 4 consecutive m -> packed 8B
                f16* C = (f16*)Cv + bz * sCb;
                f16x4 pk;
                #pragma unroll
                for (int r = 0; r < 4; ++r)
                    pk[r] = (f16)(acc[i][j][r] * scale + bv);
                *(f16x4*)&C[(long long)gn * M + gm] = pk;
            }
        }
    }
}

__global__ __launch_bounds__(256)
void cast_to_f16(const float* __restrict__ in, f16* __restrict__ out, int n)
{
    const int i = (blockIdx.x * 256 + threadIdx.x) * 4;
    if (i < n) {
        const float4 v = *(const float4*)&in[i];
        f16x4 o;
        o[0] = (f16)v.x; o[1] = (f16)v.y; o[2] = (f16)v.z; o[3] = (f16)v.w;
        *(f16x4*)&out[i] = o;
    }
}

// out[n][k] = (f16) in[k][n], in: [rows=K][cols=N] fp32
__global__ void transpose_cast(const float* __restrict__ in, f16* __restrict__ out,
                               int rows, int cols)
{
    __shared__ f16 tile[32][33];
    const int bx = blockIdx.x * 32;  // col base (n)
    const int by = blockIdx.y * 32;  // row base (k)
    const int tx = threadIdx.x;      // 0..31
    const int ty = threadIdx.y;      // 0..7
    #pragma unroll
    for (int i = 0; i < 32; i += 8)
        tile[ty + i][tx] = (f16)in[(long long)(by + ty + i) * cols + (bx + tx)];
    __syncthreads();
    #pragma unroll
    for (int i = 0; i < 32; i += 8)
        out[(long long)(bx + ty + i) * rows + (by + tx)] = tile[tx][ty + i];
}

// One block per score row (b,q). S must be 2048 (8 elems/thread * 256 threads).
__global__ __launch_bounds__(256)
void softmax_causal(const float* __restrict__ Sc, f16* __restrict__ P, int S)
{
    const long long row = blockIdx.x;
    const int q = (int)(row % S);
    const float* src = Sc + row * S;
    f16* dst = P + row * S;
    const int t = threadIdx.x;
    __shared__ float redm[4], reds[4];

    float v[8];
    float mx = -3.0e38f;
    #pragma unroll
    for (int i = 0; i < 8; ++i) {
        const int k = t + i * 256;
        v[i] = src[k];
        if (k <= q) mx = fmaxf(mx, v[i]);
    }
    #pragma unroll
    for (int o = 32; o > 0; o >>= 1) mx = fmaxf(mx, __shfl_down(mx, o));
    if ((t & 63) == 0) redm[t >> 6] = mx;
    __syncthreads();
    mx = fmaxf(fmaxf(redm[0], redm[1]), fmaxf(redm[2], redm[3]));

    float sum = 0.f;
    #pragma unroll
    for (int i = 0; i < 8; ++i) {
        const int k = t + i * 256;
        v[i] = (k <= q) ? __expf(v[i] - mx) : 0.f;
        sum += v[i];
    }
    #pragma unroll
    for (int o = 32; o > 0; o >>= 1) sum += __shfl_down(sum, o);
    if ((t & 63) == 0) reds[t >> 6] = sum;
    __syncthreads();
    sum = reds[0] + reds[1] + reds[2] + reds[3];
    const float inv = 1.f / sum;
    #pragma unroll
    for (int i = 0; i < 8; ++i)
        dst[t + i * 256] = (f16)(v[i] * inv);
}

extern "C" void kernel_launch(void* const* d_in, const int* in_sizes, int n_in,
                              void* d_out, int out_size, void* d_ws, size_t ws_size,
                              hipStream_t stream)
{
    const float* x  = (const float*)d_in[0];
    const float* Wq = (const float*)d_in[1];
    const float* bq = (const float*)d_in[2];
    const float* Wk = (const float*)d_in[3];
    const float* bk = (const float*)d_in[4];
    const float* Wv = (const float*)d_in[5];
    const float* bv = (const float*)d_in[6];
    const float* Wo = (const float*)d_in[7];
    const float* bo = (const float*)d_in[8];
    float* out = (float*)d_out;

    const int B = 4, S = 2048, D = 1024;
    const long long SD = (long long)S * D;      // 2,097,152
    const long long SS = (long long)S * S;      // 4,194,304
    const long long BSD = (long long)B * SD;    // 8,388,608

    char* p = (char*)d_ws;
    f16*   xb  = (f16*)p;   p += BSD * 2;       // x in f16 [B*S, D]      16.8 MB
    f16*   Wqt = (f16*)p;   p += (long long)D * D * 2;
    f16*   Wkt = (f16*)p;   p += (long long)D * D * 2;
    f16*   Wvt = (f16*)p;   p += (long long)D * D * 2;
    f16*   Wot = (f16*)p;   p += (long long)D * D * 2;  // W^T f16, 8.4 MB total
    f16*   Qb  = (f16*)p;   p += BSD * 2;       // Q f16 [B][S][D]
    f16*   Kb  = (f16*)p;   p += BSD * 2;       // K f16 [B][S][D]
    f16*   Vt  = (f16*)p;   p += BSD * 2;       // V^T f16 [B][D][S]
    float* Sc  = (float*)p; p += (long long)B * SS * 4; // scores fp32, 67 MB
    f16*   Pb  = (f16*)p;   p += (long long)B * SS * 2; // probs f16, 34 MB
    f16*   Ab  = xb;  // attn output aliases xb (x dead after QKV projections)

    // 1) casts
    cast_to_f16<<<dim3((unsigned)(BSD / 4 / 256)), dim3(256), 0, stream>>>(x, xb, (int)BSD);
    dim3 tb(32, 8), tg(D / 32, D / 32);
    transpose_cast<<<tg, tb, 0, stream>>>(Wq, Wqt, D, D);
    transpose_cast<<<tg, tb, 0, stream>>>(Wk, Wkt, D, D);
    transpose_cast<<<tg, tb, 0, stream>>>(Wv, Wvt, D, D);
    transpose_cast<<<tg, tb, 0, stream>>>(Wo, Wot, D, D);

    // 2) projections: [S,D] @ [D,D]^T(t) + b, batched over B
    dim3 blk(256);
    dim3 gproj(D / BN, S / BM, B);
    gemm_bt<1, 0><<<gproj, blk, 0, stream>>>(xb, Wqt, bq, Qb, S, D, D, SD, 0, SD, 1.f);
    gemm_bt<1, 0><<<gproj, blk, 0, stream>>>(xb, Wkt, bk, Kb, S, D, D, SD, 0, SD, 1.f);
    gemm_bt<2, 0><<<gproj, blk, 0, stream>>>(xb, Wvt, bv, Vt, S, D, D, SD, 0, SD, 1.f); // V^T

    // 3) scores = Q K^T / 8, causal block skip, fp32 out
    dim3 gsc(S / BN, S / BM, B);
    gemm_bt<0, 1><<<gsc, blk, 0, stream>>>(Qb, Kb, nullptr, Sc, S, S, D, SD, SD, SS, 0.125f);

    // 4) causal softmax -> P (f16), zeros in masked region
    softmax_causal<<<dim3((unsigned)(B * S)), dim3(256), 0, stream>>>(Sc, Pb, S);

    // 5) attn = P @ V  (B operand = V^T rows), K-loop limited to m0+BM
    dim3 gpv(D / BN, S / BM, B);
    gemm_bt<1, 2><<<gpv, blk, 0, stream>>>(Pb, Vt, nullptr, Ab, S, D, S, SS, SD, SD, 1.f);

    // 6) out = attn @ Wo^T(t) + bo, fp32
    gemm_bt<0, 0><<<gpv, blk, 0, stream>>>(Ab, Wot, bo, out, S, D, D, SD, 0, SD, 1.f);
}

// Round 2
// 320.289 us; speedup vs baseline: 1.0791x; 1.0791x over previous
//
#include <hip/hip_runtime.h>
#include <stdint.h>

typedef _Float16 f16;
typedef __attribute__((ext_vector_type(8))) _Float16 f16x8;
typedef __attribute__((ext_vector_type(4))) _Float16 f16x4;
typedef __attribute__((ext_vector_type(4))) float f32x4;

#define BM 128
#define BN 128
#define BK 32

typedef __attribute__((address_space(3))) uint32_t lds_u32;
typedef const __attribute__((address_space(1))) uint32_t glb_u32;

__device__ __forceinline__ void gload_lds16(const void* g, void* l) {
    // async global->LDS, 16B per lane; LDS dest = wave-uniform base + lane*16
    __builtin_amdgcn_global_load_lds((glb_u32*)g, (lds_u32*)l, 16, 0, 0);
}

// C[M,N] = A[M,K] * B[N,K]^T  (both f16 row-major), fp32 accumulate.
// OUT_MODE: 0 = fp32 flat [M,N] + bias
//           1 = f16 out, per-batch stride sCb, row-major [M,N] + bias
//           3 = fused QKV: gn<1024 -> Q flat f16 [M,1024]; <2048 -> K flat;
//               else V^T f16 [B][1024][2048] (batch from gm>>11)
// CAUSAL: 0 = none (grid x=N-tiles, y=M-tiles)
//         1 = lower-triangle only: blockIdx.x is flattened triangular id
//         2 = PV: K-loop limit m0+BM; diagonal pairing — block y does
//             m-tiles y and (M/BM-1-y); gridDim.y = M/BM/2
template<int OUT_MODE, int CAUSAL>
__global__ __launch_bounds__(256, 2)
void gemm_bt(const f16* __restrict__ A, const f16* __restrict__ B,
             const float* __restrict__ bias, const float* __restrict__ bias2,
             const float* __restrict__ bias3,
             void* __restrict__ Cv, void* __restrict__ C2, void* __restrict__ C3,
             int M, int N, int K,
             long long sAb, long long sBb, long long sCb, float scale)
{
    int mtile, n0;
    if (CAUSAL == 1) {
        int rem = (int)blockIdx.x, mi = 0;
        while (rem > mi) { rem -= mi + 1; ++mi; }   // row mi has mi+1 n-blocks
        mtile = mi;
        n0 = rem * BN;
    } else {
        mtile = blockIdx.y;
        n0 = blockIdx.x * BN;
    }

    const int tid  = threadIdx.x;
    const int wave = tid >> 6;
    const int lane = tid & 63;
    const long long bz = blockIdx.z;
    A += bz * sAb;
    B += bz * sBb;

    __shared__ f16 As[BM * BK];  // A tile, rows = m  ([128][32], 64B rows)
    __shared__ f16 Bs[BM * BK];  // B^T tile, rows = n

    const int wm = (wave >> 1) * 64;
    const int wn = (wave & 1) * 64;

    const int srow = lane >> 2;         // staging: row within 16-row group
    const int scol = (lane & 3) * 8;    // staging: 8-elem (16B) chunk in row
    const int fr   = lane & 15;         // frag: m (A) / n (B) within 16-tile
    const int fk   = (lane >> 4) * 8;   // frag: k offset (quad*8)

    const int npass = (CAUSAL == 2) ? 2 : 1;
    for (int pass = 0; pass < npass; ++pass) {
        const int mt = (CAUSAL == 2 && pass == 1) ? (M / BM - 1 - mtile) : mtile;
        const int m0 = mt * BM;
        const int Kend = (CAUSAL == 2) ? (m0 + BM) : K;

        f32x4 acc[4][4] = {};

        for (int k0 = 0; k0 < Kend; k0 += BK) {
            #pragma unroll
            for (int i = 0; i < 2; ++i) {
                const int r = wave * 32 + i * 16;  // wave-uniform 16-row group
                gload_lds16(A + (long long)(m0 + r + srow) * K + (k0 + scol), &As[r * BK]);
                gload_lds16(B + (long long)(n0 + r + srow) * K + (k0 + scol), &Bs[r * BK]);
            }
            __syncthreads();

            f16x8 af[4], bf[4];
            #pragma unroll
            for (int i = 0; i < 4; ++i)
                af[i] = *(const f16x8*)&As[(wm + i * 16 + fr) * BK + fk];
            #pragma unroll
            for (int j = 0; j < 4; ++j)
                bf[j] = *(const f16x8*)&Bs[(wn + j * 16 + fr) * BK + fk];

            #pragma unroll
            for (int i = 0; i < 4; ++i)
                #pragma unroll
                for (int j = 0; j < 4; ++j)
                    acc[i][j] = __builtin_amdgcn_mfma_f32_16x16x32_f16(af[i], bf[j], acc[i][j], 0, 0, 0);
            __syncthreads();
        }

        // Epilogue. C/D layout: col = lane&15, row = (lane>>4)*4 + reg  [m89/m91]
        const int cn = lane & 15;
        const int cm = (lane >> 4) * 4;
        #pragma unroll
        for (int j = 0; j < 4; ++j) {
            const int gn = n0 + wn + j * 16 + cn;
            #pragma unroll
            for (int i = 0; i < 4; ++i) {
                const int gm = m0 + wm + i * 16 + cm;
                if (OUT_MODE == 0) {
                    const float bv = bias ? bias[gn] : 0.f;
                    float* C = (float*)Cv + bz * sCb;
                    #pragma unroll
                    for (int r = 0; r < 4; ++r)
                        C[(long long)(gm + r) * N + gn] = acc[i][j][r] * scale + bv;
                } else if (OUT_MODE == 1) {
                    const float bv = bias ? bias[gn] : 0.f;
                    f16* C = (f16*)Cv + bz * sCb;
                    #pragma unroll
                    for (int r = 0; r < 4; ++r)
                        C[(long long)(gm + r) * N + gn] = (f16)(acc[i][j][r] * scale + bv);
                } else {  // OUT_MODE == 3, fused QKV epilogue
                    const int sel = gn >> 10;
                    const int nn  = gn & 1023;
                    const float* bp = (sel == 0) ? bias : (sel == 1) ? bias2 : bias3;
                    const float bv = bp[nn];
                    if (sel < 2) {
                        f16* C = (f16*)((sel == 0) ? Cv : C2);
                        #pragma unroll
                        for (int r = 0; r < 4; ++r)
                            C[(long long)(gm + r) * 1024 + nn] = (f16)(acc[i][j][r] + bv);
                    } else {
                        f16* C = (f16*)C3;
                        const int b = gm >> 11, s = gm & 2047;
                        f16x4 pk;
                        #pragma unroll
                        for (int r = 0; r < 4; ++r)
                            pk[r] = (f16)(acc[i][j][r] + bv);
                        *(f16x4*)&C[(long long)b * 2097152 + (long long)nn * 2048 + s] = pk;
                    }
                }
            }
        }
        if (CAUSAL == 2) __syncthreads();  // LDS reuse across passes
    }
}

__global__ __launch_bounds__(256)
void cast_to_f16(const float* __restrict__ in, f16* __restrict__ out, int n)
{
    const int i = (blockIdx.x * 256 + threadIdx.x) * 4;
    if (i < n) {
        const float4 v = *(const float4*)&in[i];
        f16x4 o;
        o[0] = (f16)v.x; o[1] = (f16)v.y; o[2] = (f16)v.z; o[3] = (f16)v.w;
        *(f16x4*)&out[i] = o;
    }
}

// out[n][k] = (f16) in[k][n], in: [rows][cols] fp32
__global__ void transpose_cast(const float* __restrict__ in, f16* __restrict__ out,
                               int rows, int cols)
{
    __shared__ f16 tile[32][33];
    const int bx = blockIdx.x * 32;  // col base (n)
    const int by = blockIdx.y * 32;  // row base (k)
    const int tx = threadIdx.x;      // 0..31
    const int ty = threadIdx.y;      // 0..7
    #pragma unroll
    for (int i = 0; i < 32; i += 8)
        tile[ty + i][tx] = (f16)in[(long long)(by + ty + i) * cols + (bx + tx)];
    __syncthreads();
    #pragma unroll
    for (int i = 0; i < 32; i += 8)
        out[(long long)(bx + ty + i) * rows + (by + tx)] = tile[tx][ty + i];
}

// One block per score row (b,q). S = 2048: 8 f16/thread, one 16B load each.
__global__ __launch_bounds__(256)
void softmax_causal(const f16* __restrict__ Sc, f16* __restrict__ P, int S)
{
    const long long row = blockIdx.x;
    const int q = (int)(row % S);
    const f16* src = Sc + row * S;
    f16* dst = P + row * S;
    const int t = threadIdx.x;
    __shared__ float redm[4], reds[4];

    const f16x8 vv = *(const f16x8*)&src[t * 8];
    float v[8];
    float mx = -3.0e38f;
    #pragma unroll
    for (int i = 0; i < 8; ++i) {
        const int k = t * 8 + i;
        v[i] = (float)vv[i];
        if (k <= q) mx = fmaxf(mx, v[i]);
    }
    #pragma unroll
    for (int o = 32; o > 0; o >>= 1) mx = fmaxf(mx, __shfl_down(mx, o));
    if ((t & 63) == 0) redm[t >> 6] = mx;
    __syncthreads();
    mx = fmaxf(fmaxf(redm[0], redm[1]), fmaxf(redm[2], redm[3]));

    float sum = 0.f;
    #pragma unroll
    for (int i = 0; i < 8; ++i) {
        const int k = t * 8 + i;
        v[i] = (k <= q) ? __expf(v[i] - mx) : 0.f;
        sum += v[i];
    }
    #pragma unroll
    for (int o = 32; o > 0; o >>= 1) sum += __shfl_down(sum, o);
    if ((t & 63) == 0) reds[t >> 6] = sum;
    __syncthreads();
    sum = reds[0] + reds[1] + reds[2] + reds[3];
    const float inv = 1.f / sum;
    f16x8 ov;
    #pragma unroll
    for (int i = 0; i < 8; ++i) ov[i] = (f16)(v[i] * inv);
    *(f16x8*)&dst[t * 8] = ov;
}

extern "C" void kernel_launch(void* const* d_in, const int* in_sizes, int n_in,
                              void* d_out, int out_size, void* d_ws, size_t ws_size,
                              hipStream_t stream)
{
    const float* x  = (const float*)d_in[0];
    const float* Wq = (const float*)d_in[1];
    const float* bq = (const float*)d_in[2];
    const float* Wk = (const float*)d_in[3];
    const float* bk = (const float*)d_in[4];
    const float* Wv = (const float*)d_in[5];
    const float* bv = (const float*)d_in[6];
    const float* Wo = (const float*)d_in[7];
    const float* bo = (const float*)d_in[8];
    float* out = (float*)d_out;

    const int B = 4, S = 2048, D = 1024;
    const long long SD  = (long long)S * D;      // 2,097,152
    const long long SS  = (long long)S * S;      // 4,194,304
    const long long BSD = (long long)B * SD;     // 8,388,608
    const int MS = B * S;                        // 8192 flat rows

    char* p = (char*)d_ws;
    f16*   xb   = (f16*)p;  p += BSD * 2;                 // x f16 [8192,1024]
    f16*   Wcat = (f16*)p;  p += 3LL * D * D * 2;         // [Wq^T;Wk^T;Wv^T] f16 [3072,1024]
    f16*   Wot  = (f16*)p;  p += (long long)D * D * 2;    // Wo^T f16
    f16*   Qb   = (f16*)p;  p += BSD * 2;                 // Q f16 [8192,1024]
    f16*   Kb   = (f16*)p;  p += BSD * 2;                 // K f16 [8192,1024]
    f16*   Vt   = (f16*)p;  p += BSD * 2;                 // V^T f16 [B][1024][2048]
    f16*   Sc   = (f16*)p;  p += (long long)B * SS * 2;   // scores f16 [B][S][S]
    f16*   Pb   = (f16*)p;  p += (long long)B * SS * 2;   // probs f16
    f16*   Ab   = xb;  // attn out aliases xb (x dead after QKV projection)

    // 1) casts
    cast_to_f16<<<dim3((unsigned)(BSD / 4 / 256)), dim3(256), 0, stream>>>(x, xb, (int)BSD);
    dim3 tb(32, 8), tg(D / 32, D / 32);
    transpose_cast<<<tg, tb, 0, stream>>>(Wq, Wcat,             D, D);
    transpose_cast<<<tg, tb, 0, stream>>>(Wk, Wcat + D * D,     D, D);
    transpose_cast<<<tg, tb, 0, stream>>>(Wv, Wcat + 2 * D * D, D, D);
    transpose_cast<<<tg, tb, 0, stream>>>(Wo, Wot,              D, D);

    dim3 blk(256);

    // 2) fused QKV projection: [8192,1024] @ [3072,1024]^T -> Q,K flat; V^T batched
    dim3 gqkv(3 * D / BN, MS / BM, 1);   // 24 x 64 = 1536 blocks
    gemm_bt<3, 0><<<gqkv, blk, 0, stream>>>(xb, Wcat, bq, bk, bv, Qb, Kb, Vt,
                                            MS, 3 * D, D, 0, 0, 0, 1.f);

    // 3) scores = Q K^T / 8, lower-triangle blocks only (136 per batch), f16 out
    dim3 gsc(136, 1, B);
    gemm_bt<1, 1><<<gsc, blk, 0, stream>>>(Qb, Kb, nullptr, nullptr, nullptr,
                                           Sc, nullptr, nullptr,
                                           S, S, D, SD, SD, SS, 0.125f);

    // 4) causal softmax -> P (f16)
    softmax_causal<<<dim3((unsigned)(B * S)), blk, 0, stream>>>(Sc, Pb, S);

    // 5) attn = P @ V; diagonal-paired m-tiles for uniform work (8 pairs)
    dim3 gpv(D / BN, S / BM / 2, B);     // 8 x 8 x 4 = 256 blocks, 2 m-tiles each
    gemm_bt<1, 2><<<gpv, blk, 0, stream>>>(Pb, Vt, nullptr, nullptr, nullptr,
                                           Ab, nullptr, nullptr,
                                           S, D, S, SS, SD, SD, 1.f);

    // 6) out = attn @ Wo^T + bo, fp32, flat M=8192
    dim3 gop(D / BN, MS / BM, 1);        // 8 x 64 = 512 blocks
    gemm_bt<0, 0><<<gop, blk, 0, stream>>>(Ab, Wot, bo, nullptr, nullptr,
                                           out, nullptr, nullptr,
                                           MS, D, D, 0, 0, 0, 1.f);
}